// Round 1
// baseline (754.413 us; speedup 1.0000x reference)
//
#include <hip/hip_runtime.h>
#include <math.h>

#define BB 512
#define DD 512
#define KK 93431

#define S_SCALEf 64.0f
#define COS_Mf   0.87758256189037276f   /* cos(0.5) */
#define SIN_Mf   0.47942553860420301f   /* sin(0.5) */
#define THRESHf (-0.87758256189037276f) /* cos(pi-0.5) */
#define MMf      0.23971276930210151f   /* sin(pi-0.5)*0.5 */
#define EPSf     0.1f
#define MFIXf    65.0f

#define NT 64   /* cols per block  */
#define MT 128  /* rows per block  */
#define BK 32   /* k-step          */

// ---------------- kernel 1: row-normalize x -> xn ----------------
__global__ void rownorm_k(const float* __restrict__ x, float* __restrict__ xn) {
    int b = blockIdx.x;
    int t = threadIdx.x; // 256
    float v0 = x[b * DD + t];
    float v1 = x[b * DD + t + 256];
    float ss = v0 * v0 + v1 * v1;
    for (int off = 32; off; off >>= 1) ss += __shfl_down(ss, off);
    __shared__ float wred[4];
    __shared__ float s_inv;
    if ((t & 63) == 0) wred[t >> 6] = ss;
    __syncthreads();
    if (t == 0) s_inv = rsqrtf(wred[0] + wred[1] + wred[2] + wred[3]);
    __syncthreads();
    float inv = s_inv;
    xn[b * DD + t]       = v0 * inv;
    xn[b * DD + t + 256] = v1 * inv;
}

// ---------------- kernel 2: kernel column inverse norms ----------------
__global__ void colnorm_k(const float* __restrict__ ker, float* __restrict__ invk) {
    int k = blockIdx.x * 256 + threadIdx.x;
    if (k >= KK) return;
    float ss = 0.f;
#pragma unroll 8
    for (int d = 0; d < DD; ++d) {
        float v = ker[(size_t)d * KK + k];
        ss = fmaf(v, v, ss);
    }
    invk[k] = rsqrtf(ss);
}

// ---------------- kernel 3: target logits (label columns) ----------------
__global__ void target_k(const float* __restrict__ xn, const float* __restrict__ ker,
                         const float* __restrict__ invk, const int* __restrict__ label,
                         float* __restrict__ tl) {
    int b = blockIdx.x;
    int lane = threadIdx.x; // 64
    int col = label[b];
    float acc = 0.f;
#pragma unroll
    for (int d = lane; d < DD; d += 64)
        acc = fmaf(xn[b * DD + d], ker[(size_t)d * KK + col], acc);
    for (int off = 32; off; off >>= 1) acc += __shfl_down(acc, off);
    if (lane == 0) {
        float c = acc * invk[col];
        c = fminf(1.f, fmaxf(-1.f, c));
        tl[b] = c;
    }
}

// ---------------- kernel 4: scalars (t_new, cos_theta_m, final target), zero accums ----
__global__ void scalar_k(const float* __restrict__ tl, const float* __restrict__ t_in,
                         float* __restrict__ ctm, float* __restrict__ ftl,
                         float* __restrict__ tnew, float* __restrict__ gse,
                         float* __restrict__ gsl) {
    int t = threadIdx.x; // 512
    float v = tl[t];
    __shared__ float red[8];
    __shared__ float s_tn;
    float s = v;
    for (int off = 32; off; off >>= 1) s += __shfl_down(s, off);
    if ((t & 63) == 0) red[t >> 6] = s;
    __syncthreads();
    if (t == 0) {
        float tot = 0.f;
        for (int i = 0; i < 8; ++i) tot += red[i];
        s_tn = (tot / 512.0f) * 0.01f + 0.99f * t_in[0];
        tnew[0] = s_tn;
    }
    __syncthreads();
    float st = sqrtf(fmaxf(0.f, 1.f - v * v));
    float cm = v * COS_Mf - st * SIN_Mf;
    ctm[t] = cm;
    ftl[t] = (v > THRESHf) ? cm : (v - MMf);
    gse[t] = 0.f;
    gsl[t] = 0.f;
}

// ---------------- kernel 5: fused GEMM + CurricularFace transform + row sums ----------
__global__ __launch_bounds__(256) void gemm_k(
    const float* __restrict__ xn, const float* __restrict__ ker,
    const float* __restrict__ invk, const int* __restrict__ label,
    const float* __restrict__ ctm, const float* __restrict__ ftl,
    const float* __restrict__ tnew,
    float* __restrict__ gse, float* __restrict__ gsl)
{
    __shared__ float As[BK][MT];      // 16 KB, k-major
    __shared__ float Bs[BK][NT];      // 8 KB, k-major
    __shared__ float lse_s[MT];
    __shared__ float lsl_s[MT];

    int t = threadIdx.x;              // 256
    int col0 = blockIdx.x * NT;
    int row0 = blockIdx.y * MT;
    int cg = t & 15;                  // 16 col-groups x 4 cols
    int rg = t >> 4;                  // 16 row-groups x 8 rows

    float acc[8][4];
#pragma unroll
    for (int i = 0; i < 8; ++i)
#pragma unroll
        for (int j = 0; j < 4; ++j) acc[i][j] = 0.f;

    for (int k0 = 0; k0 < DD; k0 += BK) {
        __syncthreads();
        // A tile: 128 rows x 32 k as 1024 float4 (xn rows are 16B-aligned)
#pragma unroll
        for (int i = 0; i < 4; ++i) {
            int lin = t + 256 * i;          // 0..1023
            int r  = lin >> 3;              // 0..127
            int kv = lin & 7;               // float4 index in BK
            const float4 v = *reinterpret_cast<const float4*>(
                &xn[(row0 + r) * DD + k0 + kv * 4]);
            As[kv * 4 + 0][r] = v.x;
            As[kv * 4 + 1][r] = v.y;
            As[kv * 4 + 2][r] = v.z;
            As[kv * 4 + 3][r] = v.w;
        }
        // B tile: 32 k x 64 cols, scalar (K odd -> rows not 16B aligned), coalesced
#pragma unroll
        for (int i = 0; i < 8; ++i) {
            int lin = t + 256 * i;          // 0..2047
            int kk = lin >> 6;
            int c  = lin & 63;
            int col = col0 + c;
            float v = 0.f;
            if (col < KK) v = ker[(size_t)(k0 + kk) * KK + col];
            Bs[kk][c] = v;
        }
        __syncthreads();
#pragma unroll
        for (int kk = 0; kk < BK; ++kk) {
            float4 a0 = *reinterpret_cast<const float4*>(&As[kk][rg * 8]);
            float4 a1 = *reinterpret_cast<const float4*>(&As[kk][rg * 8 + 4]);
            float4 b  = *reinterpret_cast<const float4*>(&Bs[kk][cg * 4]);
            float av[8] = {a0.x, a0.y, a0.z, a0.w, a1.x, a1.y, a1.z, a1.w};
            float bv[4] = {b.x, b.y, b.z, b.w};
#pragma unroll
            for (int i = 0; i < 8; ++i)
#pragma unroll
                for (int j = 0; j < 4; ++j)
                    acc[i][j] = fmaf(av[i], bv[j], acc[i][j]);
        }
    }

    // ---- epilogue: CurricularFace transform + per-row partial sums ----
    float tn = tnew[0];
    int   cols[4];
    float invkv[4];
#pragma unroll
    for (int j = 0; j < 4; ++j) {
        cols[j] = col0 + cg * 4 + j;
        invkv[j] = (cols[j] < KK) ? invk[cols[j]] : 0.f;
    }

    float pe[8], pl[8];
#pragma unroll
    for (int i = 0; i < 8; ++i) {
        int row = row0 + rg * 8 + i;
        int lbl = label[row];
        float cm = ctm[row];
        float ft = ftl[row];
        float se = 0.f, sl = 0.f;
#pragma unroll
        for (int j = 0; j < 4; ++j) {
            if (cols[j] < KK) {
                float c = acc[i][j] * invkv[j];
                c = fminf(1.f, fmaxf(-1.f, c));
                float v = (c > cm) ? c * (tn + c) : c;
                if (cols[j] == lbl) v = ft;
                float lg = S_SCALEf * v;
                se += expf(lg - MFIXf);
                sl += lg;
            }
        }
        pe[i] = se;
        pl[i] = sl;
    }
    // reduce across the 16 lanes sharing a row-group (width-16 butterfly)
#pragma unroll
    for (int i = 0; i < 8; ++i) {
        float se = pe[i], sl = pl[i];
        for (int off = 8; off; off >>= 1) {
            se += __shfl_down(se, off, 16);
            sl += __shfl_down(sl, off, 16);
        }
        if (cg == 0) {
            lse_s[rg * 8 + i] = se;
            lsl_s[rg * 8 + i] = sl;
        }
    }
    __syncthreads();
    if (t < MT) {
        atomicAdd(&gse[row0 + t], lse_s[t]);
        atomicAdd(&gsl[row0 + t], lsl_s[t]);
    }
}

// ---------------- kernel 6: final loss ----------------
__global__ void loss_k(const float* __restrict__ gse, const float* __restrict__ gsl,
                       const float* __restrict__ ftl, float* __restrict__ out) {
    int t = threadIdx.x; // 512
    float lse = MFIXf + logf(gse[t]);
    float lbl_logit = S_SCALEf * ftl[t];
    float nll = (1.f - EPSf) * (lbl_logit - lse)
              + (EPSf / (float)KK) * (gsl[t] - (float)KK * lse);
    __shared__ float red[8];
    float s = nll;
    for (int off = 32; off; off >>= 1) s += __shfl_down(s, off);
    if ((t & 63) == 0) red[t >> 6] = s;
    __syncthreads();
    if (t == 0) {
        float tot = 0.f;
        for (int i = 0; i < 8; ++i) tot += red[i];
        out[0] = -(tot / 512.0f);
    }
}

extern "C" void kernel_launch(void* const* d_in, const int* in_sizes, int n_in,
                              void* d_out, int out_size, void* d_ws, size_t ws_size,
                              hipStream_t stream) {
    const float* x     = (const float*)d_in[0];
    const int*   label = (const int*)d_in[1];
    const float* ker   = (const float*)d_in[2];
    const float* t_in  = (const float*)d_in[3];
    float* out = (float*)d_out;

    float* ws   = (float*)d_ws;
    float* xn   = ws;                       // 262144
    float* invk = ws + 262144;              // 93431 (pad to 93440)
    float* tl   = ws + 262144 + 93440;      // 512
    float* ctm  = tl + 512;                 // 512
    float* ftl  = ctm + 512;                // 512
    float* tnew = ftl + 512;                // 1 (pad to 64)
    float* gse  = tnew + 64;                // 512
    float* gsl  = gse + 512;                // 512

    rownorm_k<<<BB, 256, 0, stream>>>(x, xn);
    colnorm_k<<<(KK + 255) / 256, 256, 0, stream>>>(ker, invk);
    target_k<<<BB, 64, 0, stream>>>(xn, ker, invk, label, tl);
    scalar_k<<<1, 512, 0, stream>>>(tl, t_in, ctm, ftl, tnew, gse, gsl);
    gemm_k<<<dim3((KK + NT - 1) / NT, BB / MT), 256, 0, stream>>>(
        xn, ker, invk, label, ctm, ftl, tnew, gse, gsl);
    loss_k<<<1, 512, 0, stream>>>(gse, gsl, ftl, out);
}

// Round 2
// 200.651 us; speedup vs baseline: 3.7598x; 3.7598x over previous
//
#include <hip/hip_runtime.h>
#include <math.h>

#define BB 512
#define DD 512
#define KK 93431
#define KPAD 93440

#define S_SCALEf 64.0f
#define COS_Mf   0.87758256189037276f   /* cos(0.5) */
#define SIN_Mf   0.47942553860420301f   /* sin(0.5) */
#define THRESHf (-0.87758256189037276f) /* cos(pi-0.5) */
#define MMf      0.23971276930210151f   /* sin(pi-0.5)*0.5 */
#define EPSf     0.1f
#define MFIXf    65.0f

typedef __bf16 bf16x8 __attribute__((ext_vector_type(8)));
typedef float  f32x4  __attribute__((ext_vector_type(4)));
typedef unsigned short ushort8 __attribute__((ext_vector_type(8)));

__device__ __forceinline__ unsigned short f2bf(float f) {
    union { float f; unsigned u; } v; v.f = f;
    unsigned r = v.u + 0x7FFFu + ((v.u >> 16) & 1u);   // RNE
    return (unsigned short)(r >> 16);
}

__device__ __forceinline__ void gload16(const void* g, void* l) {
    __builtin_amdgcn_global_load_lds(
        (const __attribute__((address_space(1))) unsigned int*)g,
        (__attribute__((address_space(3))) unsigned int*)l, 16, 0, 0);
}

// ---------------- kernel 1: row-normalize x -> xn (f32) + xnb (bf16) ----------------
__global__ void rownorm_k(const float* __restrict__ x, float* __restrict__ xn,
                          unsigned short* __restrict__ xnb) {
    int b = blockIdx.x;
    int t = threadIdx.x; // 256
    float v0 = x[b * DD + t];
    float v1 = x[b * DD + t + 256];
    float ss = v0 * v0 + v1 * v1;
    for (int off = 32; off; off >>= 1) ss += __shfl_down(ss, off);
    __shared__ float wred[4];
    __shared__ float s_inv;
    if ((t & 63) == 0) wred[t >> 6] = ss;
    __syncthreads();
    if (t == 0) s_inv = rsqrtf(wred[0] + wred[1] + wred[2] + wred[3]);
    __syncthreads();
    float inv = s_inv;
    float a0 = v0 * inv, a1 = v1 * inv;
    xn[b * DD + t]        = a0;
    xn[b * DD + t + 256]  = a1;
    xnb[b * DD + t]       = f2bf(a0);
    xnb[b * DD + t + 256] = f2bf(a1);
}

// ------------- kernel 2: transpose+convert kernel matrix, partial column sumsq -------
__global__ __launch_bounds__(256) void tcvt_k(const float* __restrict__ ker,
                                              unsigned short* __restrict__ kerbt,
                                              float* __restrict__ ssq) {
    __shared__ float tile[64][65];
    __shared__ float sp[256];
    int t = threadIdx.x;
    int c0 = blockIdx.x * 64;           // 1460 tiles cover KPAD
    int d0 = blockIdx.y * 64;           // 8 tiles cover DD
    int lc = t & 63;
    int dq = t >> 6;                    // 0..3
    int gc = c0 + lc;
    bool valid = gc < KK;
    float ss = 0.f;
#pragma unroll
    for (int i = 0; i < 16; ++i) {
        int d = dq + i * 4;
        float v = valid ? ker[(size_t)(d0 + d) * KK + gc] : 0.f;
        tile[d][lc] = v;
        ss = fmaf(v, v, ss);
    }
    sp[t] = ss;
    __syncthreads();
    if (t < 64 && (c0 + t) < KK) {
        float tot = sp[t] + sp[t + 64] + sp[t + 128] + sp[t + 192];
        atomicAdd(&ssq[c0 + t], tot);
    }
    // write transposed bf16: kerbt[col][d]
#pragma unroll
    for (int j = 0; j < 2; ++j) {
        int l = t + 256 * j;            // 0..511
        int c = l >> 3;                 // 0..63
        int dc = l & 7;                 // 8-elem chunk
        ushort8 o;
#pragma unroll
        for (int e = 0; e < 8; ++e) o[e] = f2bf(tile[dc * 8 + e][c]);
        *reinterpret_cast<ushort8*>(&kerbt[(size_t)(c0 + c) * DD + d0 + dc * 8]) = o;
    }
}

// ---------------- kernel 3: ssq -> invk ----------------
__global__ void invk_k(const float* __restrict__ ssq, float* __restrict__ invk) {
    int i = blockIdx.x * 256 + threadIdx.x;
    if (i < KPAD) invk[i] = (i < KK) ? rsqrtf(ssq[i]) : 0.f;
}

// ---------------- kernel 4: target logits (label columns, fp32) ----------------
__global__ void target_k(const float* __restrict__ xn, const float* __restrict__ ker,
                         const float* __restrict__ invk, const int* __restrict__ label,
                         float* __restrict__ tl) {
    int b = blockIdx.x;
    int lane = threadIdx.x; // 64
    int col = label[b];
    float acc = 0.f;
#pragma unroll
    for (int d = lane; d < DD; d += 64)
        acc = fmaf(xn[b * DD + d], ker[(size_t)d * KK + col], acc);
    for (int off = 32; off; off >>= 1) acc += __shfl_down(acc, off);
    if (lane == 0) {
        float c = acc * invk[col];
        c = fminf(1.f, fmaxf(-1.f, c));
        tl[b] = c;
    }
}

// ---------------- kernel 5: scalars (t_new, cos_theta_m, final target) ----------
__global__ void scalar_k(const float* __restrict__ tl, const float* __restrict__ t_in,
                         float* __restrict__ ctm, float* __restrict__ ftl,
                         float* __restrict__ tnew) {
    int t = threadIdx.x; // 512
    float v = tl[t];
    __shared__ float red[8];
    __shared__ float s_tn;
    float s = v;
    for (int off = 32; off; off >>= 1) s += __shfl_down(s, off);
    if ((t & 63) == 0) red[t >> 6] = s;
    __syncthreads();
    if (t == 0) {
        float tot = 0.f;
        for (int i = 0; i < 8; ++i) tot += red[i];
        s_tn = (tot / 512.0f) * 0.01f + 0.99f * t_in[0];
        tnew[0] = s_tn;
    }
    __syncthreads();
    float st = sqrtf(fmaxf(0.f, 1.f - v * v));
    float cm = v * COS_Mf - st * SIN_Mf;
    ctm[t] = cm;
    ftl[t] = (v > THRESHf) ? cm : (v - MMf);
}

// ------------- kernel 6: bf16 MFMA GEMM + CurricularFace epilogue + row sums -------
#define BM 128
#define BN 128
#define BKg 64
#define NXBLK 730   /* KPAD/BN */
#define NWG  2920   /* NXBLK*4 */

__global__ __launch_bounds__(256) void gemm_k(
    const unsigned short* __restrict__ xnb,    // [512][512] bf16
    const unsigned short* __restrict__ kerbt,  // [KPAD][512] bf16
    const float* __restrict__ invk,
    const int* __restrict__ label,
    const float* __restrict__ ctm, const float* __restrict__ ftl,
    const float* __restrict__ tnew,
    float* __restrict__ gse, float* __restrict__ gsl)
{
    __shared__ __align__(16) unsigned short As[BM * BKg];  // 16 KB, swizzled
    __shared__ __align__(16) unsigned short Bs[BN * BKg];  // 16 KB, swizzled
    __shared__ float se_s[BM], sl_s[BM];
    __shared__ float ctm_s[BM], ftl_s[BM];
    __shared__ int   lbl_s[BM];

    // XCD chunk swizzle (2920 % 8 == 0 -> bijective), y-inner decomposition
    int wg = blockIdx.x;
    int id = (wg & 7) * (NWG / 8) + (wg >> 3);
    int by = id & 3;
    int bx = id >> 2;
    int col0 = bx * BN;
    int row0 = by * BM;

    int t = threadIdx.x;
    int lane = t & 63;
    int w = t >> 6;
    int wm = w >> 1, wn = w & 1;

    if (t < BM) {
        se_s[t] = 0.f; sl_s[t] = 0.f;
        int r = row0 + t;
        ctm_s[t] = ctm[r]; ftl_s[t] = ftl[r]; lbl_s[t] = label[r];
    }

    f32x4 acc[4][4];
#pragma unroll
    for (int i = 0; i < 4; ++i)
#pragma unroll
        for (int j = 0; j < 4; ++j) acc[i][j] = 0.f;

    int swz = (lane & 7) << 4;          // read-side XOR (r&7 == lane&7 for frags)
    const char* Ap = (const char*)As;
    const char* Bp = (const char*)Bs;
    int kbyte = (lane >> 4) * 16;       // 8-bf16 chunk within 32-k group
    int rbase = wm * 64 + (lane & 15);
    int cbase = wn * 64 + (lane & 15);

    for (int k0 = 0; k0 < DD; k0 += BKg) {
        // stage A and B tiles: 1024 chunks of 16B each; source pre-swizzled
#pragma unroll
        for (int j = 0; j < 4; ++j) {
            int l = t + 256 * j;        // 0..1023
            int r = l >> 3;
            int kc = (l & 7) ^ (r & 7);
            gload16(&xnb[(size_t)(row0 + r) * DD + k0 + kc * 8], (void*)&As[l * 8]);
            gload16(&kerbt[(size_t)(col0 + r) * DD + k0 + kc * 8], (void*)&Bs[l * 8]);
        }
        __syncthreads();   // drains vmcnt -> staged data visible
#pragma unroll
        for (int ks = 0; ks < 2; ++ks) {
            bf16x8 af[4], bf[4];
#pragma unroll
            for (int f = 0; f < 4; ++f) {
                int aoff = (((rbase + f * 16) * 128) + ks * 64 + kbyte) ^ swz;
                int boff = (((cbase + f * 16) * 128) + ks * 64 + kbyte) ^ swz;
                af[f] = *reinterpret_cast<const bf16x8*>(Ap + aoff);
                bf[f] = *reinterpret_cast<const bf16x8*>(Bp + boff);
            }
#pragma unroll
            for (int i = 0; i < 4; ++i)
#pragma unroll
                for (int j = 0; j < 4; ++j)
                    acc[i][j] = __builtin_amdgcn_mfma_f32_16x16x32_bf16(
                        af[i], bf[j], acc[i][j], 0, 0, 0);
        }
        __syncthreads();   // protect LDS reuse
    }

    // ---- fused CurricularFace epilogue ----
    float tn = tnew[0];
    int mycol[4]; float myinv[4];
#pragma unroll
    for (int fn = 0; fn < 4; ++fn) {
        int c = col0 + wn * 64 + fn * 16 + (lane & 15);
        mycol[fn] = c;
        myinv[fn] = invk[c];
    }
#pragma unroll
    for (int fm = 0; fm < 4; ++fm) {
#pragma unroll
        for (int reg = 0; reg < 4; ++reg) {
            int row = wm * 64 + fm * 16 + ((lane >> 4) << 2) + reg; // block-local
            float cm = ctm_s[row], ft = ftl_s[row];
            int lbl = lbl_s[row];
            float se = 0.f, sl = 0.f;
#pragma unroll
            for (int fn = 0; fn < 4; ++fn) {
                if (mycol[fn] < KK) {
                    float c = acc[fm][fn][reg] * myinv[fn];
                    c = fminf(1.f, fmaxf(-1.f, c));
                    float v = (c > cm) ? c * (tn + c) : c;
                    if (mycol[fn] == lbl) v = ft;
                    float lg = S_SCALEf * v;
                    se += __expf(lg - MFIXf);
                    sl += lg;
                }
            }
#pragma unroll
            for (int off = 8; off; off >>= 1) {
                se += __shfl_down(se, off, 16);
                sl += __shfl_down(sl, off, 16);
            }
            if ((lane & 15) == 0) {
                atomicAdd(&se_s[row], se);
                atomicAdd(&sl_s[row], sl);
            }
        }
    }
    __syncthreads();
    if (t < BM) {
        atomicAdd(&gse[row0 + t], se_s[t]);
        atomicAdd(&gsl[row0 + t], sl_s[t]);
    }
}

// ---------------- kernel 7: final loss ----------------
__global__ void loss_k(const float* __restrict__ gse, const float* __restrict__ gsl,
                       const float* __restrict__ ftl, float* __restrict__ out) {
    int t = threadIdx.x; // 512
    float lse = MFIXf + logf(gse[t]);
    float lbl_logit = S_SCALEf * ftl[t];
    float nll = (1.f - EPSf) * (lbl_logit - lse)
              + (EPSf / (float)KK) * (gsl[t] - (float)KK * lse);
    __shared__ float red[8];
    float s = nll;
    for (int off = 32; off; off >>= 1) s += __shfl_down(s, off);
    if ((t & 63) == 0) red[t >> 6] = s;
    __syncthreads();
    if (t == 0) {
        float tot = 0.f;
        for (int i = 0; i < 8; ++i) tot += red[i];
        out[0] = -(tot / 512.0f);
    }
}

extern "C" void kernel_launch(void* const* d_in, const int* in_sizes, int n_in,
                              void* d_out, int out_size, void* d_ws, size_t ws_size,
                              hipStream_t stream) {
    const float* x     = (const float*)d_in[0];
    const int*   label = (const int*)d_in[1];
    const float* ker   = (const float*)d_in[2];
    const float* t_in  = (const float*)d_in[3];
    float* out = (float*)d_out;

    float* ws   = (float*)d_ws;
    float* xn   = ws;                 // 262144
    float* ssq  = xn + 262144;        // 93440
    float* gse  = ssq + KPAD;         // 512
    float* gsl  = gse + 512;          // 512
    float* tl   = gsl + 512;          // 512
    float* ctm  = tl + 512;           // 512
    float* ftl  = ctm + 512;          // 512
    float* tnew = ftl + 512;          // 64
    float* invk = tnew + 64;          // 93440
    unsigned short* xnb   = (unsigned short*)(invk + KPAD);  // 262144 bf16
    unsigned short* kerbt = xnb + 262144;                    // KPAD*512 bf16

    // zero ssq + gse + gsl (contiguous region)
    hipMemsetAsync(ssq, 0, (KPAD + 1024) * sizeof(float), stream);

    rownorm_k<<<BB, 256, 0, stream>>>(x, xn, xnb);
    tcvt_k<<<dim3(KPAD / 64, DD / 64), 256, 0, stream>>>(ker, kerbt, ssq);
    invk_k<<<KPAD / 256, 256, 0, stream>>>(ssq, invk);
    target_k<<<BB, 64, 0, stream>>>(xn, ker, invk, label, tl);
    scalar_k<<<1, 512, 0, stream>>>(tl, t_in, ctm, ftl, tnew);
    gemm_k<<<NWG, 256, 0, stream>>>(xnb, kerbt, invk, label, ctm, ftl, tnew, gse, gsl);
    loss_k<<<1, 512, 0, stream>>>(gse, gsl, ftl, out);
}

// Round 3
// 190.229 us; speedup vs baseline: 3.9658x; 1.0548x over previous
//
#include <hip/hip_runtime.h>
#include <math.h>

#define BB 512
#define DD 512
#define KK 93431
#define KPAD 93440

#define S_SCALEf 64.0f
#define COS_Mf   0.87758256189037276f   /* cos(0.5) */
#define SIN_Mf   0.47942553860420301f   /* sin(0.5) */
#define THRESHf (-0.87758256189037276f) /* cos(pi-0.5) */
#define MMf      0.23971276930210151f   /* sin(pi-0.5)*0.5 */
#define EPSf     0.1f
#define MFIXf    65.0f

typedef __bf16 bf16x8 __attribute__((ext_vector_type(8)));
typedef float  f32x4  __attribute__((ext_vector_type(4)));
typedef unsigned short ushort8 __attribute__((ext_vector_type(8)));

__device__ __forceinline__ unsigned short f2bf(float f) {
    union { float f; unsigned u; } v; v.f = f;
    unsigned r = v.u + 0x7FFFu + ((v.u >> 16) & 1u);   // RNE
    return (unsigned short)(r >> 16);
}

__device__ __forceinline__ void gload16(const void* g, void* l) {
    __builtin_amdgcn_global_load_lds(
        (const __attribute__((address_space(1))) unsigned int*)g,
        (__attribute__((address_space(3))) unsigned int*)l, 16, 0, 0);
}

// ---------------- kernel 1: row-normalize x -> xn (f32) + xnb (bf16) ----------------
__global__ void rownorm_k(const float* __restrict__ x, float* __restrict__ xn,
                          unsigned short* __restrict__ xnb) {
    int b = blockIdx.x;
    int t = threadIdx.x; // 256
    float v0 = x[b * DD + t];
    float v1 = x[b * DD + t + 256];
    float ss = v0 * v0 + v1 * v1;
    for (int off = 32; off; off >>= 1) ss += __shfl_down(ss, off);
    __shared__ float wred[4];
    __shared__ float s_inv;
    if ((t & 63) == 0) wred[t >> 6] = ss;
    __syncthreads();
    if (t == 0) s_inv = rsqrtf(wred[0] + wred[1] + wred[2] + wred[3]);
    __syncthreads();
    float inv = s_inv;
    float a0 = v0 * inv, a1 = v1 * inv;
    xn[b * DD + t]        = a0;
    xn[b * DD + t + 256]  = a1;
    xnb[b * DD + t]       = f2bf(a0);
    xnb[b * DD + t + 256] = f2bf(a1);
}

// ------------- kernel 2: transpose+convert kernel matrix, partial column sumsq -------
__global__ __launch_bounds__(256) void tcvt_k(const float* __restrict__ ker,
                                              unsigned short* __restrict__ kerbt,
                                              float* __restrict__ ssq) {
    __shared__ float tile[64][65];
    __shared__ float sp[256];
    int t = threadIdx.x;
    int c0 = blockIdx.x * 64;           // 1460 tiles cover KPAD
    int d0 = blockIdx.y * 64;           // 8 tiles cover DD
    int lc = t & 63;
    int dq = t >> 6;                    // 0..3
    int gc = c0 + lc;
    bool valid = gc < KK;
    float ss = 0.f;
#pragma unroll
    for (int i = 0; i < 16; ++i) {
        int d = dq + i * 4;
        float v = valid ? ker[(size_t)(d0 + d) * KK + gc] : 0.f;
        tile[d][lc] = v;
        ss = fmaf(v, v, ss);
    }
    sp[t] = ss;
    __syncthreads();
    if (t < 64 && (c0 + t) < KK) {
        float tot = sp[t] + sp[t + 64] + sp[t + 128] + sp[t + 192];
        atomicAdd(&ssq[c0 + t], tot);
    }
    // write transposed bf16: kerbt[col][d]
#pragma unroll
    for (int j = 0; j < 2; ++j) {
        int l = t + 256 * j;            // 0..511
        int c = l >> 3;                 // 0..63
        int dc = l & 7;                 // 8-elem chunk
        ushort8 o;
#pragma unroll
        for (int e = 0; e < 8; ++e) o[e] = f2bf(tile[dc * 8 + e][c]);
        *reinterpret_cast<ushort8*>(&kerbt[(size_t)(c0 + c) * DD + d0 + dc * 8]) = o;
    }
}

// ---------------- kernel 3: target logits (label columns, fp32) ----------------
__global__ void target_k(const float* __restrict__ xn, const float* __restrict__ ker,
                         const float* __restrict__ ssq, const int* __restrict__ label,
                         float* __restrict__ tl) {
    int b = blockIdx.x;
    int lane = threadIdx.x; // 64
    int col = label[b];
    float acc = 0.f;
#pragma unroll
    for (int d = lane; d < DD; d += 64)
        acc = fmaf(xn[b * DD + d], ker[(size_t)d * KK + col], acc);
    for (int off = 32; off; off >>= 1) acc += __shfl_down(acc, off);
    if (lane == 0) {
        float c = acc * rsqrtf(ssq[col]);
        c = fminf(1.f, fmaxf(-1.f, c));
        tl[b] = c;
    }
}

// ---------------- kernel 4: scalars (t_new, cos_theta_m, final target) ----------
__global__ void scalar_k(const float* __restrict__ tl, const float* __restrict__ t_in,
                         float* __restrict__ ctm, float* __restrict__ ftl,
                         float* __restrict__ tnew) {
    int t = threadIdx.x; // 512
    float v = tl[t];
    __shared__ float red[8];
    __shared__ float s_tn;
    float s = v;
    for (int off = 32; off; off >>= 1) s += __shfl_down(s, off);
    if ((t & 63) == 0) red[t >> 6] = s;
    __syncthreads();
    if (t == 0) {
        float tot = 0.f;
        for (int i = 0; i < 8; ++i) tot += red[i];
        s_tn = (tot / 512.0f) * 0.01f + 0.99f * t_in[0];
        tnew[0] = s_tn;
    }
    __syncthreads();
    float st = sqrtf(fmaxf(0.f, 1.f - v * v));
    float cm = v * COS_Mf - st * SIN_Mf;
    ctm[t] = cm;
    ftl[t] = (v > THRESHf) ? cm : (v - MMf);
}

// ------------- kernel 5: bf16 MFMA GEMM, double-buffered counted-vmcnt pipeline ----
#define BM 256
#define BN 128
#define BKg 64
#define NXBLK 730           /* KPAD/BN */
#define NWG  1460           /* NXBLK * (BB/BM) */
#define KTILES 8            /* DD/BKg */

__global__ __launch_bounds__(512) void gemm_k(
    const unsigned short* __restrict__ xnb,    // [512][512] bf16
    const unsigned short* __restrict__ kerbt,  // [KPAD][512] bf16
    const float* __restrict__ ssq,
    const int* __restrict__ label,
    const float* __restrict__ ctm, const float* __restrict__ ftl,
    const float* __restrict__ tnew,
    float* __restrict__ gse, float* __restrict__ gsl)
{
    __shared__ __align__(16) unsigned short As[2][BM * BKg];  // 2 x 32 KB
    __shared__ __align__(16) unsigned short Bs[2][BN * BKg];  // 2 x 16 KB
    __shared__ float se_s[BM], sl_s[BM];
    __shared__ float ctm_s[BM], ftl_s[BM];
    __shared__ int   lbl_s[BM];

    // bijective XCD chunk swizzle (1460 = 8*182 + 4), y-inner decomposition
    int orig = blockIdx.x;
    int xcd = orig & 7;
    int base = (xcd < 4) ? xcd * 183 : 4 * 183 + (xcd - 4) * 182;
    int id = base + (orig >> 3);
    int by = id & 1;
    int bx = id >> 1;
    int col0 = bx * BN;
    int row0 = by * BM;

    int t = threadIdx.x;               // 512
    int lane = t & 63;
    int w = t >> 6;                    // 8 waves
    int wm = w >> 1;                   // 0..3 (64-row slice)
    int wn = w & 1;                    // 0..1 (64-col slice)

    if (t < BM) {
        se_s[t] = 0.f; sl_s[t] = 0.f;
        int r = row0 + t;
        ctm_s[t] = ctm[r]; ftl_s[t] = ftl[r]; lbl_s[t] = label[r];
    }

    f32x4 acc[4][4];
#pragma unroll
    for (int i = 0; i < 4; ++i)
#pragma unroll
        for (int j = 0; j < 4; ++j) acc[i][j] = 0.f;

    const int swz = (lane & 7) << 4;
    const int kbyte = (lane >> 4) * 16;
    const int rbase = wm * 64 + (lane & 15);
    const int cbase = wn * 64 + (lane & 15);

    // ---- prologue: stage tile 0 into buffer 0 (6 loads/thread) ----
#pragma unroll
    for (int j = 0; j < 4; ++j) {
        int l = t + 512 * j;           // 0..2047 -> A chunks
        int r = l >> 3;
        int kc = (l & 7) ^ (r & 7);
        gload16(&xnb[(size_t)(row0 + r) * DD + kc * 8], (void*)&As[0][l * 8]);
    }
#pragma unroll
    for (int j = 0; j < 2; ++j) {
        int l = t + 512 * j;           // 0..1023 -> B chunks
        int r = l >> 3;
        int kc = (l & 7) ^ (r & 7);
        gload16(&kerbt[(size_t)(col0 + r) * DD + kc * 8], (void*)&Bs[0][l * 8]);
    }
    __builtin_amdgcn_sched_barrier(0);

    // ---- main loop: counted-vmcnt double-buffered pipeline ----
    for (int kt = 0; kt < KTILES; ++kt) {
        const int cur = kt & 1;
        if (kt < KTILES - 1) {
            const int nxt = cur ^ 1;
            const int kn0 = (kt + 1) * BKg;
#pragma unroll
            for (int j = 0; j < 4; ++j) {
                int l = t + 512 * j;
                int r = l >> 3;
                int kc = (l & 7) ^ (r & 7);
                gload16(&xnb[(size_t)(row0 + r) * DD + kn0 + kc * 8],
                        (void*)&As[nxt][l * 8]);
            }
#pragma unroll
            for (int j = 0; j < 2; ++j) {
                int l = t + 512 * j;
                int r = l >> 3;
                int kc = (l & 7) ^ (r & 7);
                gload16(&kerbt[(size_t)(col0 + r) * DD + kn0 + kc * 8],
                        (void*)&Bs[nxt][l * 8]);
            }
            __builtin_amdgcn_sched_barrier(0);
            asm volatile("s_waitcnt vmcnt(6)" ::: "memory");   // tile kt done, kt+1 in flight
        } else {
            asm volatile("s_waitcnt vmcnt(0)" ::: "memory");
        }
        __builtin_amdgcn_s_barrier();
        __builtin_amdgcn_sched_barrier(0);

        __builtin_amdgcn_s_setprio(1);
        const char* Ap = (const char*)&As[cur][0];
        const char* Bp = (const char*)&Bs[cur][0];
#pragma unroll
        for (int ks = 0; ks < 2; ++ks) {
            bf16x8 af[4], bfr[4];
#pragma unroll
            for (int f = 0; f < 4; ++f) {
                int aoff = ((rbase + f * 16) * 128 + ks * 64 + kbyte) ^ swz;
                int boff = ((cbase + f * 16) * 128 + ks * 64 + kbyte) ^ swz;
                af[f]  = *reinterpret_cast<const bf16x8*>(Ap + aoff);
                bfr[f] = *reinterpret_cast<const bf16x8*>(Bp + boff);
            }
#pragma unroll
            for (int i = 0; i < 4; ++i)
#pragma unroll
                for (int j = 0; j < 4; ++j)
                    acc[i][j] = __builtin_amdgcn_mfma_f32_16x16x32_bf16(
                        af[i], bfr[j], acc[i][j], 0, 0, 0);
        }
        __builtin_amdgcn_s_setprio(0);
        asm volatile("s_waitcnt lgkmcnt(0)" ::: "memory");
        __builtin_amdgcn_sched_barrier(0);
        __builtin_amdgcn_s_barrier();      // buf cur free for overwrite next iter
    }

    // ---- fused CurricularFace epilogue ----
    float tn = tnew[0];
    int mycol[4]; float myinv[4];
#pragma unroll
    for (int fn = 0; fn < 4; ++fn) {
        int c = col0 + wn * 64 + fn * 16 + (lane & 15);
        mycol[fn] = c;
        myinv[fn] = rsqrtf(ssq[c]);        // ssq>0 for c<KK; pad cols unused
    }
#pragma unroll
    for (int fm = 0; fm < 4; ++fm) {
#pragma unroll
        for (int reg = 0; reg < 4; ++reg) {
            int row = wm * 64 + fm * 16 + ((lane >> 4) << 2) + reg; // block-local
            float cm = ctm_s[row], ft = ftl_s[row];
            int lbl = lbl_s[row];
            float se = 0.f, sl = 0.f;
#pragma unroll
            for (int fn = 0; fn < 4; ++fn) {
                if (mycol[fn] < KK) {
                    float c = acc[fm][fn][reg] * myinv[fn];
                    c = fminf(1.f, fmaxf(-1.f, c));
                    float v = (c > cm) ? c * (tn + c) : c;
                    if (mycol[fn] == lbl) v = ft;
                    float lg = S_SCALEf * v;
                    se += __expf(lg - MFIXf);
                    sl += lg;
                }
            }
#pragma unroll
            for (int off = 8; off; off >>= 1) {
                se += __shfl_down(se, off, 16);
                sl += __shfl_down(sl, off, 16);
            }
            if ((lane & 15) == 0) {
                atomicAdd(&se_s[row], se);
                atomicAdd(&sl_s[row], sl);
            }
        }
    }
    __syncthreads();
    if (t < BM) {
        atomicAdd(&gse[row0 + t], se_s[t]);
        atomicAdd(&gsl[row0 + t], sl_s[t]);
    }
}

// ---------------- kernel 6: final loss ----------------
__global__ void loss_k(const float* __restrict__ gse, const float* __restrict__ gsl,
                       const float* __restrict__ ftl, float* __restrict__ out) {
    int t = threadIdx.x; // 512
    float lse = MFIXf + logf(gse[t]);
    float lbl_logit = S_SCALEf * ftl[t];
    float nll = (1.f - EPSf) * (lbl_logit - lse)
              + (EPSf / (float)KK) * (gsl[t] - (float)KK * lse);
    __shared__ float red[8];
    float s = nll;
    for (int off = 32; off; off >>= 1) s += __shfl_down(s, off);
    if ((t & 63) == 0) red[t >> 6] = s;
    __syncthreads();
    if (t == 0) {
        float tot = 0.f;
        for (int i = 0; i < 8; ++i) tot += red[i];
        out[0] = -(tot / 512.0f);
    }
}

extern "C" void kernel_launch(void* const* d_in, const int* in_sizes, int n_in,
                              void* d_out, int out_size, void* d_ws, size_t ws_size,
                              hipStream_t stream) {
    const float* x     = (const float*)d_in[0];
    const int*   label = (const int*)d_in[1];
    const float* ker   = (const float*)d_in[2];
    const float* t_in  = (const float*)d_in[3];
    float* out = (float*)d_out;

    float* ws   = (float*)d_ws;
    float* xn   = ws;                 // 262144
    float* ssq  = xn + 262144;        // 93440
    float* gse  = ssq + KPAD;         // 512
    float* gsl  = gse + 512;          // 512
    float* tl   = gsl + 512;          // 512
    float* ctm  = tl + 512;           // 512
    float* ftl  = ctm + 512;          // 512
    float* tnew = ftl + 512;          // 64
    unsigned short* xnb   = (unsigned short*)(tnew + 64);    // 262144 bf16
    unsigned short* kerbt = xnb + 262144;                    // KPAD*512 bf16

    // zero ssq + gse + gsl (contiguous region)
    hipMemsetAsync(ssq, 0, (KPAD + 1024) * sizeof(float), stream);

    rownorm_k<<<BB, 256, 0, stream>>>(x, xn, xnb);
    tcvt_k<<<dim3(KPAD / 64, DD / 64), 256, 0, stream>>>(ker, kerbt, ssq);
    target_k<<<BB, 64, 0, stream>>>(xn, ker, ssq, label, tl);
    scalar_k<<<1, 512, 0, stream>>>(tl, t_in, ctm, ftl, tnew);
    gemm_k<<<NWG, 512, 0, stream>>>(xnb, kerbt, ssq, label, ctm, ftl, tnew, gse, gsl);
    loss_k<<<1, 512, 0, stream>>>(gse, gsl, ftl, out);
}